// Round 1
// baseline (1146.568 us; speedup 1.0000x reference)
//
#include <hip/hip_runtime.h>

// 2-layer LSTM, B=2048, T=4096, IN=1, H=8, OUT=1, fp32.
//
// R9 = R8 structure, vectorized 2-sequences-per-wave with packed FP32
// (v_pk_fma_f32 / v_pk_mul_f32 / v_pk_add_f32, full-rate on gfx950).
// Every state scalar becomes float2 (.x = seqA, .y = seqB); weights are
// splat pairs; shuffles (DPP / ds_swizzle / ds_bpermute) and
// transcendentals (exp2 / rcp) run per component.
// 1024 waves (1/SIMD), 256 blocks x 256 threads.
//
// Layout within a seq-pair: lane = L*32 + j*4 + g (g=gate i,f,g~,o;
// j=unit; L=layer). Near h (units j..j^3) via 5 intra-row DPPs per
// component. Far-half dot: each lane computes the far partial OF ITS
// MIRROR LANE's row from its near h, ships via ds_swizzle xor16.
// Cross-layer: d2 ships via ds_bpermute lane^32, consumed TWO iterations
// later: recvB(m) = d2(m-2) = Wih1 . h1(m-3)  =>  L1 runs THREE iters
// behind L0. Projection dot at iter m uses h2(m-4) -> store op[m-4];
// fills = iters 0,1,2; first L1 step at iter 3; steady m = 4..Tsz+3.
// Gates pre-scaled by -log2e (g~ rows -2log2e): act = rcp(1+exp2(z)).
// All L1 lanes hold the identical projection value, so lane 32 stores
// seqA (.x) and lane 33 stores seqB (.y).

constexpr int Bsz = 2048;
constexpr int Tsz = 4096;

typedef float v2f __attribute__((ext_vector_type(2)));
typedef float v4f __attribute__((ext_vector_type(4)));

template <int CTRL>
__device__ __forceinline__ float dpp1(float v) {
    return __int_as_float(
        __builtin_amdgcn_mov_dpp(__float_as_int(v), CTRL, 0xF, 0xF, true));
}
// quad_perm bcast0..3 = 0x00,0x55,0xAA,0xFF; quad xor3 = 0x1B;
// row_half_mirror (xor7) = 0x141; row_mirror (xor15) = 0x140
template <int CTRL>
__device__ __forceinline__ v2f dpp2(v2f v) {
    v2f r; r.x = dpp1<CTRL>(v.x); r.y = dpp1<CTRL>(v.y); return r;
}

__device__ __forceinline__ float swz16f(float v) {
    // ds_swizzle bit mode, xor 0x10 within each 32-lane group
    return __int_as_float(
        __builtin_amdgcn_ds_swizzle(__float_as_int(v), (16 << 10) | 0x1f));
}
__device__ __forceinline__ v2f swz16v(v2f v) {
    v2f r; r.x = swz16f(v.x); r.y = swz16f(v.y); return r;
}

__device__ __forceinline__ float bpermf(int addr, float v) {
    return __int_as_float(__builtin_amdgcn_ds_bpermute(addr, __float_as_int(v)));
}
__device__ __forceinline__ v2f bpermv(int addr, v2f v) {
    v2f r; r.x = bpermf(addr, v.x); r.y = bpermf(addr, v.y); return r;
}

// gfx90a+/gfx950 packed fp32: 64-bit VGPR-pair operands, 2 x f32 per inst.
__device__ __forceinline__ v2f pk_fma(v2f a, v2f b, v2f c) {
    v2f d;
    asm("v_pk_fma_f32 %0, %1, %2, %3" : "=v"(d) : "v"(a), "v"(b), "v"(c));
    return d;
}
__device__ __forceinline__ v2f pk_mul(v2f a, v2f b) {
    v2f d;
    asm("v_pk_mul_f32 %0, %1, %2" : "=v"(d) : "v"(a), "v"(b));
    return d;
}
__device__ __forceinline__ v2f pk_add(v2f a, v2f b) {
    v2f d;
    asm("v_pk_add_f32 %0, %1, %2" : "=v"(d) : "v"(a), "v"(b));
    return d;
}

__global__ void __launch_bounds__(256, 1) lstm2_pk2(
    const float* __restrict__ x,      // [B, T]
    const float* __restrict__ Wih0,   // [32, 1]
    const float* __restrict__ Whh0,   // [32, 8]
    const float* __restrict__ bih0,   // [32]
    const float* __restrict__ bhh0,   // [32]
    const float* __restrict__ Wih1,   // [32, 8]
    const float* __restrict__ Whh1,   // [32, 8]
    const float* __restrict__ bih1,   // [32]
    const float* __restrict__ bhh1,   // [32]
    const float* __restrict__ Wlin,   // [1, 8]
    const float* __restrict__ blin,   // [1]
    float* __restrict__ out)          // [B, T]
{
    const int tid  = threadIdx.x;
    const int lane = tid & 63;
    const int g    = lane & 3;
    const int j    = (lane >> 2) & 7;
    const int L    = (lane >> 5) & 1;
    const int wid  = blockIdx.x * 4 + (tid >> 6);   // 0..1023
    const int seq0 = wid * 2;                        // seqA; seqB = seq0+1

    const int jm = j ^ 4;             // mirror lane's unit
    const int r  = g * 8 + j;         // own gate row
    const int rm = g * 8 + jm;        // mirror lane's gate row

    const float NL2E  = -1.4426950408889634f;
    const float N2L2E = -2.8853900817779268f;
    const bool  isG   = (g == 2);
    const float ws    = isG ? N2L2E : NL2E;
    const float sAct  = isG ? 2.0f : 1.0f;      // tanh = 2*sig(2z)-1
    const float oAct  = isG ? -1.0f : 0.0f;

    const float* __restrict__ Whh = L ? Whh1 : Whh0;
    const float* __restrict__ bih = L ? bih1 : bih0;
    const float* __restrict__ bhh = L ? bhh1 : bhh0;

    // near weights (own row) + mirror-row weights, k = j^i for i=0..3,
    // splatted into both packed halves (same weights for both sequences)
    v2f wn1[4], wm1[4], wn2[4], wm2[4];
#pragma unroll
    for (int i = 0; i < 4; ++i) {
        const int k = j ^ i;
        const float a1 = Whh[r * 8 + k] * ws;
        const float a2 = Whh[rm * 8 + k] * ws;
        const float a3 = L ? Wlin[k] : Wih1[r * 8 + k] * ws;
        const float a4 = L ? Wlin[k] : Wih1[rm * 8 + k] * ws;
        wn1[i] = (v2f){a1, a1};
        wm1[i] = (v2f){a2, a2};
        wn2[i] = (v2f){a3, a3};
        wm2[i] = (v2f){a4, a4};
    }
    const float biasS = (bih[r] + bhh[r]) * ws;
    const float wxS   = L ? 0.0f : Wih0[r] * ws;
    const float b2S   = L ? blin[0] : 0.0f;
    const float mLS   = L ? 1.0f : 0.0f;
    const float kpS   = 1.0f - mLS;
    const v2f biasp = (v2f){biasS, biasS};
    const v2f wxp   = (v2f){wxS, wxS};
    const v2f b2p   = (v2f){b2S, b2S};
    const v2f mLp   = (v2f){mLS, mLS};
    const v2f keepp = (v2f){kpS, kpS};
    const v2f n2l2p = (v2f){N2L2E, N2L2E};
    const int  xaddr = (lane ^ 32) * 4;   // bpermute: cross layer halves

    const float* __restrict__ xpA = x + (size_t)seq0 * Tsz;
    const float* __restrict__ xpB = x + (size_t)(seq0 + 1) * Tsz;
    // all L1 lanes hold the identical projection; lane32 -> .x, lane33 -> .y
    const bool storeLane = (lane == 32) || (lane == 33);
    float* __restrict__ myop = out + (size_t)(seq0 + (lane & 1)) * Tsz;

    v2f hn0 = (v2f){0.f, 0.f}, hn1 = hn0, hn2 = hn0, hn3 = hn0;
    v2f c = hn0, h = hn0;
    v2f recvA = hn0, recvB = hn0;

    auto body = [&](v2f xt, bool fill, int sidx) {
        // -- mirror partials from entering hn (= h(m-1)); ship early
        v2f am1 = pk_mul(wm1[0], hn0);
        am1 = pk_fma(wm1[1], hn1, am1);
        am1 = pk_fma(wm1[2], hn2, am1);
        am1 = pk_fma(wm1[3], hn3, am1);
        v2f am2 = pk_mul(wm2[0], hn0);
        am2 = pk_fma(wm2[1], hn1, am2);
        am2 = pk_fma(wm2[2], hn2, am2);
        am2 = pk_fma(wm2[3], hn3, am2);
        const v2f s1 = swz16v(am1);   // far half of OWN row's hh-dot
        const v2f s2 = swz16v(am2);   // far half of OWN row's spare dot

        // -- near dots
        v2f an1 = pk_fma(wxp, xt, biasp);
        an1 = pk_fma(wn1[0], hn0, an1);
        an1 = pk_fma(wn1[1], hn1, an1);
        an1 = pk_fma(wn1[2], hn2, an1);
        an1 = pk_fma(wn1[3], hn3, an1);
        v2f an2 = pk_fma(wn2[0], hn0, b2p);
        an2 = pk_fma(wn2[1], hn1, an2);
        an2 = pk_fma(wn2[2], hn2, an2);
        an2 = pk_fma(wn2[3], hn3, an2);

        // -- z: near + far(ship) + cross-layer dot from 2 iters ago
        const v2f z = pk_fma(mLp, recvB, pk_add(an1, s1));

        // -- activation (pre-scaled): sig or tanh; per-component trans
        v2f a;
        a.x = fmaf(sAct,
                   __builtin_amdgcn_rcpf(1.0f + __builtin_amdgcn_exp2f(z.x)),
                   oAct);
        a.y = fmaf(sAct,
                   __builtin_amdgcn_rcpf(1.0f + __builtin_amdgcn_exp2f(z.y)),
                   oAct);
        const v2f gi = dpp2<0x00>(a);
        const v2f gf = dpp2<0x55>(a);
        const v2f gG = dpp2<0xAA>(a);
        const v2f go = dpp2<0xFF>(a);
        c = pk_fma(gf, c, pk_mul(gi, gG));
        const v2f cm = pk_mul(c, n2l2p);
        v2f th;
        th.x = fmaf(2.0f,
                    __builtin_amdgcn_rcpf(1.0f + __builtin_amdgcn_exp2f(cm.x)),
                    -1.0f);
        th.y = fmaf(2.0f,
                    __builtin_amdgcn_rcpf(1.0f + __builtin_amdgcn_exp2f(cm.y)),
                    -1.0f);
        h = pk_mul(go, th);

        if (fill) { h = pk_mul(h, keepp); c = pk_mul(c, keepp); }

        // -- near-h gather for next iter (intra-row DPP only)
        const v2f m7  = dpp2<0x141>(h);      // ^7
        const v2f m15 = dpp2<0x140>(h);      // ^15
        hn0 = h;                             // j
        hn1 = dpp2<0x1B>(m7);                // ^7^3  = ^4  -> j^1
        hn2 = dpp2<0x141>(m15);              // ^15^7 = ^8  -> j^2
        hn3 = dpp2<0x1B>(m15);               // ^15^3 = ^12 -> j^3

        // -- tail: full spare dot (uses h(m-1) values), store, ship
        const v2f d2 = pk_add(an2, s2);      // L0: Wih1.h1(m-1); L1: proj(h2(m-4))
        if (sidx >= 0 && storeLane)
            myop[sidx] = (lane & 1) ? d2.y : d2.x;
        recvB = recvA;                       // recvB for iter m+1 = d2(m-1)
        recvA = bpermv(xaddr, d2);           // d2(m)
    };

    // ---- fills: iters 0,1,2 keep L1 state zero; iter 3 = L1 step 0
    body((v2f){xpA[0], xpB[0]}, true, -1);
    body((v2f){xpA[1], xpB[1]}, true, -1);
    body((v2f){xpA[2], xpB[2]}, true, -1);
    body((v2f){xpA[3], xpB[3]}, false, -1);  // computes h2(0); proj invalid

    // ---- steady, unrolled x4: m = 4 .. Tsz+3, store op[m-4]
    v4f xcA = *(const v4f*)(xpA + 4);         // x(4..7), Tsz >> 8, 16B aligned
    v4f xcB = *(const v4f*)(xpB + 4);
    for (int ck = 0; ck < Tsz / 4; ++ck) {
        const int base = 4 + 4 * ck;
        int pidx = base + 4;
        if (pidx > Tsz - 4) pidx = Tsz - 4;   // clamp: values unused for output
        const v4f xfA = *(const v4f*)(xpA + pidx);   // prefetch next chunk
        const v4f xfB = *(const v4f*)(xpB + pidx);
#pragma unroll
        for (int u = 0; u < 4; ++u)
            body((v2f){xcA[u], xcB[u]}, false, 4 * ck + u);   // op[m-4]
        xcA = xfA; xcB = xfB;
    }
}

extern "C" void kernel_launch(void* const* d_in, const int* in_sizes, int n_in,
                              void* d_out, int out_size, void* d_ws, size_t ws_size,
                              hipStream_t stream) {
    const float* x    = (const float*)d_in[0];
    const float* Wih0 = (const float*)d_in[1];
    const float* Whh0 = (const float*)d_in[2];
    const float* bih0 = (const float*)d_in[3];
    const float* bhh0 = (const float*)d_in[4];
    const float* Wih1 = (const float*)d_in[5];
    const float* Whh1 = (const float*)d_in[6];
    const float* bih1 = (const float*)d_in[7];
    const float* bhh1 = (const float*)d_in[8];
    const float* Wlin = (const float*)d_in[9];
    const float* blin = (const float*)d_in[10];
    float* out = (float*)d_out;

    dim3 grid(Bsz / 8);   // 2 seqs/wave, 4 waves/block -> 256 blocks, 1024 waves
    dim3 block(256);
    hipLaunchKernelGGL(lstm2_pk2, grid, block, 0, stream,
                       x, Wih0, Whh0, bih0, bhh0,
                       Wih1, Whh1, bih1, bhh1, Wlin, blin, out);
}

// Round 3
// 1011.494 us; speedup vs baseline: 1.1335x; 1.1335x over previous
//
#include <hip/hip_runtime.h>

// 2-layer LSTM, B=2048, T=4096, IN=1, H=8, OUT=1, fp32.
//
// R11 = R10 intent (replace all DS-pipe cross-lane ops with gfx950
// full-rate VALU permlane swaps), but using the COMPILER BUILTINS
// (__builtin_amdgcn_permlane{16,32}_swap) instead of inline asm.
// R10's inline asm used two "+v" operands initialized from the same
// value; the allocator could coalesce them into one register, and the
// same-register form leaves odd-row lanes with their own value ->
// half-lane corruption (absmax 4.3e-2). The builtin models both results
// distinctly, so this cannot happen.
//
//   ds_swizzle xor16  -> permlane16_swap (+1 cndmask)
//   ds_bpermute xor32 -> permlane32_swap (+1 cndmask)
//
// Layout: 1 seq/wave64, lane = L*32 + j*4 + g (g=gate i,f,g~,o; j=unit;
// L=layer). Near h (units j..j^3) via 5 intra-row DPPs. Far-half dot:
// each lane computes the far partial OF ITS MIRROR LANE's row (weights
// W[row(lane^16)][j^i]) from its near h, ships via permlane16_swap.
// Cross-layer: d2 ships via permlane32_swap, consumed TWO iterations
// later: recvB(m) = d2(m-2) = Wih1 . h1(m-3)  =>  L1 runs THREE iters
// behind L0. Projection dot at iter m uses h2(m-4) -> store op[m-4];
// fills = iters 0,1,2; first L1 step at iter 3; steady m = 4..Tsz+3.
// Gates pre-scaled by -log2e (g~ rows -2log2e): act = rcp(1+exp2(z)).
//
// permlane swap semantics (both inputs = v, rows of 16/32 lanes):
//   p = swap(v, v): p.x[odd rows] = v[lane^W], p.x[even rows] = v[lane]
//                   p.y[even rows] = v[lane^W], p.y[odd rows] = v[lane]
//   => v[lane^W] = (lane & W) ? p.x : p.y

constexpr int Bsz = 2048;
constexpr int Tsz = 4096;

typedef int v2i __attribute__((ext_vector_type(2)));

template <int CTRL>
__device__ __forceinline__ float dpp(float v) {
    return __int_as_float(
        __builtin_amdgcn_mov_dpp(__float_as_int(v), CTRL, 0xF, 0xF, true));
}
// quad_perm bcast0..3 = 0x00,0x55,0xAA,0xFF; quad xor3 = 0x1B;
// row_half_mirror (xor7) = 0x141; row_mirror (xor15) = 0x140

// v[lane^16] via V_PERMLANE16_SWAP_B32 (VALU, full-rate; no DS pipe).
__device__ __forceinline__ float xchg16(float v, bool hi16) {
    const int vi = __float_as_int(v);
    v2i p = __builtin_amdgcn_permlane16_swap(vi, vi, false, false);
    return __int_as_float(hi16 ? p.x : p.y);
}

// v[lane^32] via V_PERMLANE32_SWAP_B32.
__device__ __forceinline__ float xchg32(float v, bool hi32) {
    const int vi = __float_as_int(v);
    v2i p = __builtin_amdgcn_permlane32_swap(vi, vi, false, false);
    return __int_as_float(hi32 ? p.x : p.y);
}

__global__ void __launch_bounds__(256, 2) lstm2_pl2(
    const float* __restrict__ x,      // [B, T]
    const float* __restrict__ Wih0,   // [32, 1]
    const float* __restrict__ Whh0,   // [32, 8]
    const float* __restrict__ bih0,   // [32]
    const float* __restrict__ bhh0,   // [32]
    const float* __restrict__ Wih1,   // [32, 8]
    const float* __restrict__ Whh1,   // [32, 8]
    const float* __restrict__ bih1,   // [32]
    const float* __restrict__ bhh1,   // [32]
    const float* __restrict__ Wlin,   // [1, 8]
    const float* __restrict__ blin,   // [1]
    float* __restrict__ out)          // [B, T]
{
    const int tid  = threadIdx.x;
    const int lane = tid & 63;
    const int g    = lane & 3;
    const int j    = (lane >> 2) & 7;
    const int L    = (lane >> 5) & 1;
    const int seq  = blockIdx.x * 4 + (tid >> 6);

    const int jm = j ^ 4;             // mirror lane's unit
    const int r  = g * 8 + j;         // own gate row
    const int rm = g * 8 + jm;        // mirror lane's gate row

    const bool hi16 = (lane & 16) != 0;
    const bool hi32 = (lane & 32) != 0;

    const float NL2E  = -1.4426950408889634f;
    const float N2L2E = -2.8853900817779268f;
    const bool  isG   = (g == 2);
    const float ws    = isG ? N2L2E : NL2E;
    const float sA    = isG ? 2.0f : 1.0f;      // tanh = 2*sig(2z)-1
    const float oA    = isG ? -1.0f : 0.0f;

    const float* __restrict__ Whh = L ? Whh1 : Whh0;
    const float* __restrict__ bih = L ? bih1 : bih0;
    const float* __restrict__ bhh = L ? bhh1 : bhh0;

    // near weights (own row) + mirror-row weights, k = j^i for i=0..3
    float wn1[4], wm1[4], wn2[4], wm2[4];
#pragma unroll
    for (int i = 0; i < 4; ++i) {
        const int k = j ^ i;
        wn1[i] = Whh[r * 8 + k] * ws;
        wm1[i] = Whh[rm * 8 + k] * ws;
        wn2[i] = L ? Wlin[k] : Wih1[r * 8 + k] * ws;
        wm2[i] = L ? Wlin[k] : Wih1[rm * 8 + k] * ws;
    }
    const float bias = (bih[r] + bhh[r]) * ws;
    const float wx   = L ? 0.0f : Wih0[r] * ws;
    const float b2   = L ? blin[0] : 0.0f;
    const float mL   = L ? 1.0f : 0.0f;
    const float keep = 1.0f - mL;

    const float* __restrict__ xp = x + (size_t)seq * Tsz;
    float* __restrict__ op       = out + (size_t)seq * Tsz;
    const bool storeLane = (lane == 32);

    float hn0 = 0.0f, hn1 = 0.0f, hn2 = 0.0f, hn3 = 0.0f;
    float c = 0.0f, h = 0.0f;
    float recvA = 0.0f, recvB = 0.0f;

    auto body = [&](float xt, bool fill, float* storePtr) {
        // -- mirror partials from entering hn (= h(m-1)); ship early
        float am1 = wm1[0] * hn0;
        am1 = fmaf(wm1[1], hn1, am1);
        am1 = fmaf(wm1[2], hn2, am1);
        am1 = fmaf(wm1[3], hn3, am1);
        float am2 = wm2[0] * hn0;
        am2 = fmaf(wm2[1], hn1, am2);
        am2 = fmaf(wm2[2], hn2, am2);
        am2 = fmaf(wm2[3], hn3, am2);
        const float s1 = xchg16(am1, hi16);   // far half of OWN row's hh-dot
        const float s2 = xchg16(am2, hi16);   // far half of OWN row's spare dot

        // -- near dots
        float an1 = fmaf(wx, xt, bias);
        an1 = fmaf(wn1[0], hn0, an1);
        an1 = fmaf(wn1[1], hn1, an1);
        an1 = fmaf(wn1[2], hn2, an1);
        an1 = fmaf(wn1[3], hn3, an1);
        float an2 = fmaf(wn2[0], hn0, b2);
        an2 = fmaf(wn2[1], hn1, an2);
        an2 = fmaf(wn2[2], hn2, an2);
        an2 = fmaf(wn2[3], hn3, an2);

        // -- z: near + far(ship) + cross-layer dot from 2 iters ago
        const float z = fmaf(mL, recvB, an1 + s1);

        // -- activation (pre-scaled): sig or tanh
        float a = fmaf(sA,
                       __builtin_amdgcn_rcpf(1.0f + __builtin_amdgcn_exp2f(z)),
                       oA);
        const float gi = dpp<0x00>(a);
        const float gf = dpp<0x55>(a);
        const float gG = dpp<0xAA>(a);
        const float go = dpp<0xFF>(a);
        c = fmaf(gf, c, gi * gG);
        const float e  = __builtin_amdgcn_exp2f(c * N2L2E);
        const float th = fmaf(2.0f, __builtin_amdgcn_rcpf(1.0f + e), -1.0f);
        h = go * th;

        if (fill) { h *= keep; c *= keep; }   // keep L1 state at zero

        // -- near-h gather for next iter (intra-row DPP only)
        const float m7  = dpp<0x141>(h);     // ^7
        const float m15 = dpp<0x140>(h);     // ^15
        hn0 = h;                             // j
        hn1 = dpp<0x1B>(m7);                 // ^7^3  = ^4  -> j^1
        hn2 = dpp<0x141>(m15);               // ^15^7 = ^8  -> j^2
        hn3 = dpp<0x1B>(m15);                // ^15^3 = ^12 -> j^3

        // -- tail: full spare dot (uses h(m-1) values), store, ship
        const float d2 = an2 + s2;           // L0: Wih1.h1(m-1); L1: proj(h2(m-4))
        if (storePtr && storeLane) *storePtr = d2;
        recvB = recvA;                       // recvB for iter m+1 = d2(m-1)
        recvA = xchg32(d2, hi32);            // d2(m) shipped cross-layer
    };

    // ---- fills: iters 0,1,2 keep L1 state zero; iter 3 = L1 step 0
    body(xp[0], true, nullptr);
    body(xp[1], true, nullptr);
    body(xp[2], true, nullptr);
    body(xp[3], false, nullptr);             // computes h2(0); proj invalid

    // ---- steady, unrolled x4: m = 4 .. Tsz+3, store op[m-4]
    float xc[4];
#pragma unroll
    for (int u = 0; u < 4; ++u) xc[u] = xp[4 + u];   // x(4..7), Tsz >> 8
    for (int ck = 0; ck < Tsz / 4; ++ck) {
        const int base = 4 + 4 * ck;
        float xf[4];
#pragma unroll
        for (int u = 0; u < 4; ++u) {
            int idx = base + 4 + u;
            idx = (idx < Tsz) ? idx : (Tsz - 1);
            xf[u] = xp[idx];                 // prefetch next chunk
        }
#pragma unroll
        for (int u = 0; u < 4; ++u)
            body(xc[u], false, op + (4 * ck + u));   // op[m-4]
#pragma unroll
        for (int u = 0; u < 4; ++u) xc[u] = xf[u];
    }
}

extern "C" void kernel_launch(void* const* d_in, const int* in_sizes, int n_in,
                              void* d_out, int out_size, void* d_ws, size_t ws_size,
                              hipStream_t stream) {
    const float* x    = (const float*)d_in[0];
    const float* Wih0 = (const float*)d_in[1];
    const float* Whh0 = (const float*)d_in[2];
    const float* bih0 = (const float*)d_in[3];
    const float* bhh0 = (const float*)d_in[4];
    const float* Wih1 = (const float*)d_in[5];
    const float* Whh1 = (const float*)d_in[6];
    const float* bih1 = (const float*)d_in[7];
    const float* bhh1 = (const float*)d_in[8];
    const float* Wlin = (const float*)d_in[9];
    const float* blin = (const float*)d_in[10];
    float* out = (float*)d_out;

    dim3 grid(Bsz / 4);   // 4 waves/block, 1 seq/wave -> 512 blocks, 2048 waves
    dim3 block(256);
    hipLaunchKernelGGL(lstm2_pl2, grid, block, 0, stream,
                       x, Wih0, Whh0, bih0, bhh0,
                       Wih1, Whh1, bih1, bhh1, Wlin, blin, out);
}

// Round 5
// 907.595 us; speedup vs baseline: 1.2633x; 1.1145x over previous
//
#include <hip/hip_runtime.h>

// 2-layer LSTM, B=2048, T=4096, IN=1, H=8, OUT=1, fp32.
//
// R12 = R8 hybrid. Insight from R11: of the three cross-lane ships, only
// s1 (far half of the hh-dot) is on the per-timestep critical path
// h(m-1) -> z(m). s2 and the cross-layer d2 ship are consumed 1-2
// iterations later, so DS latency there is free (hidden by slack +
// partner wave). R11 put ALL three on the VALU and lost (issue +95
// cy/pair). R12 puts ONLY s1 on the VALU permlane16_swap (verified
// bit-exact in R11), keeping s2 on ds_swizzle and d2 on ds_bpermute.
// Expect: chain loses ~60-100 cy of DS latency, issue gains ~10 cy.
//
// Layout: 1 seq/wave64, lane = L*32 + j*4 + g (g=gate i,f,g~,o; j=unit;
// L=layer). 2048 waves = 2 waves/SIMD.
// Near h (units j..j^3) via 5 intra-row DPPs. Far-half dot: each lane
// computes the far partial OF ITS MIRROR LANE's row (weights
// W[row(lane^16)][j^i]) from its near h; s1 ships via permlane16_swap,
// s2 via ds_swizzle xor16. Cross-layer: d2 ships via ds_bpermute
// lane^32, consumed TWO iterations later: recvB(m) = d2(m-2) =
// Wih1 . h1(m-3)  =>  L1 runs THREE iters behind L0. Projection dot at
// iter m uses h2(m-4) -> store op[m-4]; fills = iters 0,1,2; first L1
// step at iter 3; steady m = 4..Tsz+3.
// Gates pre-scaled by -log2e (g~ rows -2log2e): act = rcp(1+exp2(z)).

constexpr int Bsz = 2048;
constexpr int Tsz = 4096;

typedef int v2i __attribute__((ext_vector_type(2)));

template <int CTRL>
__device__ __forceinline__ float dpp(float v) {
    return __int_as_float(
        __builtin_amdgcn_mov_dpp(__float_as_int(v), CTRL, 0xF, 0xF, true));
}
// quad_perm bcast0..3 = 0x00,0x55,0xAA,0xFF; quad xor3 = 0x1B;
// row_half_mirror (xor7) = 0x141; row_mirror (xor15) = 0x140

// v[lane^16] via V_PERMLANE16_SWAP_B32 (VALU; verified bit-exact in R11).
__device__ __forceinline__ float xchg16(float v, bool hi16) {
    const int vi = __float_as_int(v);
    v2i p = __builtin_amdgcn_permlane16_swap(vi, vi, false, false);
    return __int_as_float(hi16 ? p.x : p.y);
}

__device__ __forceinline__ float swz16(float v) {
    // ds_swizzle bit mode, xor 0x10 within each 32-lane group
    return __int_as_float(
        __builtin_amdgcn_ds_swizzle(__float_as_int(v), (16 << 10) | 0x1f));
}

__device__ __forceinline__ float bperm(int addr, float v) {
    return __int_as_float(__builtin_amdgcn_ds_bpermute(addr, __float_as_int(v)));
}

__global__ void __launch_bounds__(256, 2) lstm2_hy(
    const float* __restrict__ x,      // [B, T]
    const float* __restrict__ Wih0,   // [32, 1]
    const float* __restrict__ Whh0,   // [32, 8]
    const float* __restrict__ bih0,   // [32]
    const float* __restrict__ bhh0,   // [32]
    const float* __restrict__ Wih1,   // [32, 8]
    const float* __restrict__ Whh1,   // [32, 8]
    const float* __restrict__ bih1,   // [32]
    const float* __restrict__ bhh1,   // [32]
    const float* __restrict__ Wlin,   // [1, 8]
    const float* __restrict__ blin,   // [1]
    float* __restrict__ out)          // [B, T]
{
    const int tid  = threadIdx.x;
    const int lane = tid & 63;
    const int g    = lane & 3;
    const int j    = (lane >> 2) & 7;
    const int L    = (lane >> 5) & 1;
    const int seq  = blockIdx.x * 4 + (tid >> 6);

    const int jm = j ^ 4;             // mirror lane's unit
    const int r  = g * 8 + j;         // own gate row
    const int rm = g * 8 + jm;        // mirror lane's gate row

    const bool hi16 = (lane & 16) != 0;

    const float NL2E  = -1.4426950408889634f;
    const float N2L2E = -2.8853900817779268f;
    const bool  isG   = (g == 2);
    const float ws    = isG ? N2L2E : NL2E;
    const float sA    = isG ? 2.0f : 1.0f;      // tanh = 2*sig(2z)-1
    const float oA    = isG ? -1.0f : 0.0f;

    const float* __restrict__ Whh = L ? Whh1 : Whh0;
    const float* __restrict__ bih = L ? bih1 : bih0;
    const float* __restrict__ bhh = L ? bhh1 : bhh0;

    // near weights (own row) + mirror-row weights, k = j^i for i=0..3
    float wn1[4], wm1[4], wn2[4], wm2[4];
#pragma unroll
    for (int i = 0; i < 4; ++i) {
        const int k = j ^ i;
        wn1[i] = Whh[r * 8 + k] * ws;
        wm1[i] = Whh[rm * 8 + k] * ws;
        wn2[i] = L ? Wlin[k] : Wih1[r * 8 + k] * ws;
        wm2[i] = L ? Wlin[k] : Wih1[rm * 8 + k] * ws;
    }
    const float bias = (bih[r] + bhh[r]) * ws;
    const float wx   = L ? 0.0f : Wih0[r] * ws;
    const float b2   = L ? blin[0] : 0.0f;
    const float mL   = L ? 1.0f : 0.0f;
    const float keep = 1.0f - mL;
    const int  xaddr = (lane ^ 32) * 4;   // bpermute: cross layer halves

    const float* __restrict__ xp = x + (size_t)seq * Tsz;
    float* __restrict__ op       = out + (size_t)seq * Tsz;
    const bool storeLane = (lane == 32);

    float hn0 = 0.0f, hn1 = 0.0f, hn2 = 0.0f, hn3 = 0.0f;
    float c = 0.0f, h = 0.0f;
    float recvA = 0.0f, recvB = 0.0f;

    auto body = [&](float xt, bool fill, float* storePtr) {
        // -- mirror partials from entering hn (= h(m-1))
        float am2 = wm2[0] * hn0;
        am2 = fmaf(wm2[1], hn1, am2);
        am2 = fmaf(wm2[2], hn2, am2);
        am2 = fmaf(wm2[3], hn3, am2);
        const float s2 = swz16(am2);   // off-chain: ship via DS, consumed at tail

        float am1 = wm1[0] * hn0;
        am1 = fmaf(wm1[1], hn1, am1);
        am1 = fmaf(wm1[2], hn2, am1);
        am1 = fmaf(wm1[3], hn3, am1);
        const float s1 = xchg16(am1, hi16);   // ON-CHAIN: VALU permlane swap

        // -- near dots
        float an1 = fmaf(wx, xt, bias);
        an1 = fmaf(wn1[0], hn0, an1);
        an1 = fmaf(wn1[1], hn1, an1);
        an1 = fmaf(wn1[2], hn2, an1);
        an1 = fmaf(wn1[3], hn3, an1);
        float an2 = fmaf(wn2[0], hn0, b2);
        an2 = fmaf(wn2[1], hn1, an2);
        an2 = fmaf(wn2[2], hn2, an2);
        an2 = fmaf(wn2[3], hn3, an2);

        // -- z: near + far(ship) + cross-layer dot from 2 iters ago
        const float z = fmaf(mL, recvB, an1 + s1);

        // -- activation (pre-scaled): sig or tanh
        float a = fmaf(sA,
                       __builtin_amdgcn_rcpf(1.0f + __builtin_amdgcn_exp2f(z)),
                       oA);
        const float gi = dpp<0x00>(a);
        const float gf = dpp<0x55>(a);
        const float gG = dpp<0xAA>(a);
        const float go = dpp<0xFF>(a);
        c = fmaf(gf, c, gi * gG);
        const float e  = __builtin_amdgcn_exp2f(c * N2L2E);
        const float th = fmaf(2.0f, __builtin_amdgcn_rcpf(1.0f + e), -1.0f);
        h = go * th;

        if (fill) { h *= keep; c *= keep; }   // keep L1 state at zero

        // -- near-h gather for next iter (intra-row DPP only)
        const float m7  = dpp<0x141>(h);     // ^7
        const float m15 = dpp<0x140>(h);     // ^15
        hn0 = h;                             // j
        hn1 = dpp<0x1B>(m7);                 // ^7^3  = ^4  -> j^1
        hn2 = dpp<0x141>(m15);               // ^15^7 = ^8  -> j^2
        hn3 = dpp<0x1B>(m15);                // ^15^3 = ^12 -> j^3

        // -- tail: full spare dot (uses h(m-1) values), store, ship
        const float d2 = an2 + s2;           // L0: Wih1.h1(m-1); L1: proj(h2(m-4))
        if (storePtr && storeLane) *storePtr = d2;
        recvB = recvA;                       // recvB for iter m+1 = d2(m-1)
        recvA = bperm(xaddr, d2);            // d2(m), off-chain (2-iter slack)
    };

    // ---- fills: iters 0,1,2 keep L1 state zero; iter 3 = L1 step 0
    body(xp[0], true, nullptr);
    body(xp[1], true, nullptr);
    body(xp[2], true, nullptr);
    body(xp[3], false, nullptr);             // computes h2(0); proj invalid

    // ---- steady, unrolled x4: m = 4 .. Tsz+3, store op[m-4]
    float xc[4];
#pragma unroll
    for (int u = 0; u < 4; ++u) xc[u] = xp[4 + u];   // x(4..7), Tsz >> 8
    for (int ck = 0; ck < Tsz / 4; ++ck) {
        const int base = 4 + 4 * ck;
        float xf[4];
#pragma unroll
        for (int u = 0; u < 4; ++u) {
            int idx = base + 4 + u;
            idx = (idx < Tsz) ? idx : (Tsz - 1);
            xf[u] = xp[idx];                 // prefetch next chunk
        }
#pragma unroll
        for (int u = 0; u < 4; ++u)
            body(xc[u], false, op + (4 * ck + u));   // op[m-4]
#pragma unroll
        for (int u = 0; u < 4; ++u) xc[u] = xf[u];
    }
}

extern "C" void kernel_launch(void* const* d_in, const int* in_sizes, int n_in,
                              void* d_out, int out_size, void* d_ws, size_t ws_size,
                              hipStream_t stream) {
    const float* x    = (const float*)d_in[0];
    const float* Wih0 = (const float*)d_in[1];
    const float* Whh0 = (const float*)d_in[2];
    const float* bih0 = (const float*)d_in[3];
    const float* bhh0 = (const float*)d_in[4];
    const float* Wih1 = (const float*)d_in[5];
    const float* Whh1 = (const float*)d_in[6];
    const float* bih1 = (const float*)d_in[7];
    const float* bhh1 = (const float*)d_in[8];
    const float* Wlin = (const float*)d_in[9];
    const float* blin = (const float*)d_in[10];
    float* out = (float*)d_out;

    dim3 grid(Bsz / 4);   // 4 waves/block, 1 seq/wave -> 512 blocks, 2048 waves
    dim3 block(256);
    hipLaunchKernelGGL(lstm2_hy, grid, block, 0, stream,
                       x, Wih0, Whh0, bih0, bhh0,
                       Wih1, Whh1, bih1, bhh1, Wlin, blin, out);
}